// Round 6
// baseline (1392.744 us; speedup 1.0000x reference)
//
#include <hip/hip_runtime.h>
#include <hip/hip_bf16.h>
#include <cstdint>

// ---------------------------------------------------------------------------
// LlamaMlpWithLora: T=2048, H=4096, I=11008, A=8, R=16, scale=0.5
// R6: drift-immune XCD partitioning.
//   pass1 (fused gate+up, LoRA folded into K): BM=256 (one A-slab per XCD,
//     L2-resident), BN=64, BK=64, 8 waves 4Mx2N, LDS 48KB, grid 8x172.
//   pass2 (down): 128^2 kernel, bn-fastest aligned sweeps across XCDs.
//   xa   [T][4352]  = [x | 0.5*v_g slots | 0.5*v_u slots]
//   Wg^/Wu^ [I][4352], t^ [T][11136], Wd^ [H][11136] as in R5.
// ---------------------------------------------------------------------------

#define T_TOK 2048
#define H_DIM 4096
#define I_DIM 11008
#define NA 8
#define R_LORA 16
#define KA1 4352    // H + 128(gate) + 128(up)
#define KA2 11136   // I + 128(down)

typedef __bf16 bf16x8 __attribute__((ext_vector_type(8)));
typedef float f32x4 __attribute__((ext_vector_type(4)));

__device__ __forceinline__ float bf2f(unsigned short u) {
    union { unsigned int i; float f; } v;
    v.i = ((unsigned int)u) << 16;
    return v.f;
}
__device__ __forceinline__ unsigned short f2bf(float f) {
    __bf16 b = (__bf16)f;
    unsigned short u;
    __builtin_memcpy(&u, &b, 2);
    return u;
}
__device__ __forceinline__ void cvt8(const float* s, unsigned short* d) {
    float4 a = reinterpret_cast<const float4*>(s)[0];
    float4 b = reinterpret_cast<const float4*>(s)[1];
    uint4 o;
    o.x = (unsigned)f2bf(a.x) | ((unsigned)f2bf(a.y) << 16);
    o.y = (unsigned)f2bf(a.z) | ((unsigned)f2bf(a.w) << 16);
    o.z = (unsigned)f2bf(b.x) | ((unsigned)f2bf(b.y) << 16);
    o.w = (unsigned)f2bf(b.z) | ((unsigned)f2bf(b.w) << 16);
    *reinterpret_cast<uint4*>(d) = o;
}
__device__ __forceinline__ void gload_lds16(const void* g, void* l) {
    __builtin_amdgcn_global_load_lds(
        (const __attribute__((address_space(1))) void*)g,
        (__attribute__((address_space(3))) void*)l,
        16, 0, 0);
}

// ---------------- builders -------------------------------------------------
__global__ __launch_bounds__(256) void build_w_aug(
    const float* __restrict__ w, const float* __restrict__ wb,
    unsigned short* __restrict__ dst,
    int Nrows, int Ksrc, int Kdst, int self_off, int zero_off)
{
    const int c = blockIdx.x;
    const int tid = threadIdx.x;
    const float* src = w + (size_t)c * Ksrc;
    unsigned short* d = dst + (size_t)c * Kdst;
    for (int k = tid * 8; k < Ksrc; k += 256 * 8) cvt8(src + k, d + k);
    if (tid < 128) {
        const int a = tid >> 4, r = tid & 15;
        const float v = wb[(((size_t)a * Nrows) + c) * R_LORA + r];
        d[self_off + tid] = f2bf(v);
        if (zero_off >= 0) d[zero_off + tid] = 0;
    }
}

__global__ __launch_bounds__(256) void build_xa(
    const float* __restrict__ x, const float* __restrict__ vg,
    const float* __restrict__ vu, const int* __restrict__ idx,
    unsigned short* __restrict__ dst)
{
    const int t = blockIdx.x;
    const int tid = threadIdx.x;
    const float* src = x + (size_t)t * H_DIM;
    unsigned short* d = dst + (size_t)t * KA1;
    for (int k = tid * 8; k < H_DIM; k += 2048) cvt8(src + k, d + k);
    const int a_t = idx[t];
    const int grp = tid >> 7;
    const int sub = tid & 127;
    const int a = sub >> 4, r = sub & 15;
    float v = 0.f;
    if (a == a_t) v = 0.5f * (grp ? vu : vg)[t * R_LORA + r];
    d[H_DIM + tid] = f2bf(v);
}

__global__ __launch_bounds__(128) void fill_ta(
    const float* __restrict__ vd, const int* __restrict__ idx,
    unsigned short* __restrict__ t_aug)
{
    const int t = blockIdx.x;
    const int tid = threadIdx.x;
    const int a = tid >> 4, r = tid & 15;
    float v = (a == idx[t]) ? 0.5f * vd[t * R_LORA + r] : 0.f;
    t_aug[(size_t)t * KA2 + I_DIM + tid] = f2bf(v);
}

// ---------------- LoRA v ----------------------------------------------------
__global__ __launch_bounds__(256) void lora_v_gu(
    const float* __restrict__ x, const float* __restrict__ gwa,
    const float* __restrict__ uwa, const int* __restrict__ idx,
    float* __restrict__ vg, float* __restrict__ vu)
{
    const int t = blockIdx.x;
    const int a = idx[t];
    const int wid = threadIdx.x >> 6;
    const int lane = threadIdx.x & 63;
    const float* xr = x + (size_t)t * H_DIM;
    const float* wa = (wid < 2 ? gwa : uwa) + (size_t)a * R_LORA * H_DIM;
    float* vout = (wid < 2 ? vg : vu) + t * R_LORA;
    const int r0 = (wid & 1) * 8;
    for (int r = r0; r < r0 + 8; ++r) {
        const float* w = wa + (size_t)r * H_DIM;
        float s = 0.f;
        for (int h = lane; h < H_DIM; h += 64) s += xr[h] * w[h];
        #pragma unroll
        for (int off = 32; off > 0; off >>= 1) s += __shfl_down(s, off);
        if (lane == 0) vout[r] = s;
    }
}

__global__ __launch_bounds__(256) void lora_v_down_k(
    const unsigned short* __restrict__ tmat, const float* __restrict__ dwa,
    const int* __restrict__ idx, float* __restrict__ vd)
{
    const int tok = blockIdx.x;
    const int a = idx[tok];
    const int wid = threadIdx.x >> 6;
    const int lane = threadIdx.x & 63;
    const unsigned short* tr = tmat + (size_t)tok * KA2;
    const float* wa = dwa + (size_t)a * R_LORA * I_DIM;
    #pragma unroll
    for (int rr = 0; rr < 4; ++rr) {
        const int r = wid * 4 + rr;
        const float* w = wa + (size_t)r * I_DIM;
        float s = 0.f;
        for (int h = lane; h < I_DIM; h += 64) s += bf2f(tr[h]) * w[h];
        #pragma unroll
        for (int off = 32; off > 0; off >>= 1) s += __shfl_down(s, off);
        if (lane == 0) vd[tok * R_LORA + r] = s;
    }
}

// ---------------- pass 1: fused gate+up GEMM -------------------------------
// BM=256, BN=64, BK=64. 8 waves 4Mx2N, per-wave 64x32 per matrix.
// Grid 8 bm x 172 bn, bm = blockIdx&7 -> one A-slab per XCD (L2-resident),
// bn = blockIdx>>3 -> launch-order-aligned bn sweeps (L3 serves B x8).
__global__ __launch_bounds__(512, 4) void gemm_fused_gu(
    const unsigned short* __restrict__ A,   // xa [T][KA1]
    const unsigned short* __restrict__ Bg,  // wg_aug [I][KA1]
    const unsigned short* __restrict__ Bu,  // wu_aug [I][KA1]
    unsigned short* __restrict__ Tout)      // t_aug [T][KA2]
{
    __shared__ __align__(16) unsigned short As[256][64];
    __shared__ __align__(16) unsigned short Bgs[64][64];
    __shared__ __align__(16) unsigned short Bus[64][64];

    const int tid = threadIdx.x;
    const int lane = tid & 63;
    const int wid = tid >> 6;
    const int wr = wid >> 1;           // 0..3 (M quarter)
    const int wc = wid & 1;            // 0..1 (N half)
    const int fr = lane & 15;
    const int hi = lane >> 4;
    const int fsw = fr & 7;

    const int bm0 = (blockIdx.x & 7) * 256;
    const int bn0 = (blockIdx.x >> 3) * 64;

    const int srow = tid >> 3;         // 0..63
    const int sslot = tid & 7;
    const int gcol = (sslot ^ (srow & 7)) * 8;
    const unsigned short* Ag  = A  + (size_t)(bm0 + srow) * KA1 + gcol;
    const unsigned short* Bgg = Bg + (size_t)(bn0 + srow) * KA1 + gcol;
    const unsigned short* Bug = Bu + (size_t)(bn0 + srow) * KA1 + gcol;

    f32x4 accg[4][2] = {};
    f32x4 accu[4][2] = {};

    for (int kt = 0; kt < KA1; kt += 64) {
        #pragma unroll
        for (int it = 0; it < 4; ++it)
            gload_lds16(Ag + (size_t)(it * 64) * KA1 + kt, &As[it * 64 + srow][sslot * 8]);
        gload_lds16(Bgg + kt, &Bgs[srow][sslot * 8]);
        gload_lds16(Bug + kt, &Bus[srow][sslot * 8]);
        __syncthreads();
        #pragma unroll
        for (int kk = 0; kk < 2; ++kk) {
            bf16x8 a_[4], bg_[2], bu_[2];
            #pragma unroll
            for (int m = 0; m < 4; ++m)
                a_[m] = *reinterpret_cast<const bf16x8*>(
                    &As[wr * 64 + m * 16 + fr][((kk * 4 + hi) ^ fsw) * 8]);
            #pragma unroll
            for (int n = 0; n < 2; ++n) {
                bg_[n] = *reinterpret_cast<const bf16x8*>(
                    &Bgs[wc * 32 + n * 16 + fr][((kk * 4 + hi) ^ fsw) * 8]);
                bu_[n] = *reinterpret_cast<const bf16x8*>(
                    &Bus[wc * 32 + n * 16 + fr][((kk * 4 + hi) ^ fsw) * 8]);
            }
            #pragma unroll
            for (int m = 0; m < 4; ++m)
                #pragma unroll
                for (int n = 0; n < 2; ++n) {
                    accg[m][n] = __builtin_amdgcn_mfma_f32_16x16x32_bf16(
                        a_[m], bg_[n], accg[m][n], 0, 0, 0);
                    accu[m][n] = __builtin_amdgcn_mfma_f32_16x16x32_bf16(
                        a_[m], bu_[n], accu[m][n], 0, 0, 0);
                }
        }
        __syncthreads();
    }

    // C/D layout: col = lane&15, row = (lane>>4)*4 + reg
    const int orow0 = bm0 + wr * 64 + hi * 4;
    const int ocol0 = bn0 + wc * 32 + fr;
    #pragma unroll
    for (int m = 0; m < 4; ++m)
        #pragma unroll
        for (int j = 0; j < 4; ++j) {
            const int row = orow0 + m * 16 + j;
            #pragma unroll
            for (int n = 0; n < 2; ++n) {
                const float g = accg[m][n][j];
                const float u = accu[m][n][j];
                const float sg = g / (1.f + __expf(-g));
                Tout[(size_t)row * KA2 + ocol0 + n * 16] = f2bf(sg * u);
            }
        }
}

// ---------------- pass 2: down GEMM ----------------------------------------
// 128x128 tile; per-XCD 2 bm x 32 bn with bn-fastest aligned sweeps.
__global__ __launch_bounds__(512) void gemm_down(
    const unsigned short* __restrict__ A,   // t_aug [T][KA2]
    const unsigned short* __restrict__ B,   // wd_aug [H][KA2]
    float* __restrict__ out)                // [T][H]
{
    __shared__ __align__(16) unsigned short As[128][64];
    __shared__ __align__(16) unsigned short Bs[128][64];

    const int tid = threadIdx.x;
    const int lane = tid & 63;
    const int wid = tid >> 6;
    const int wr = wid >> 2;
    const int wc = wid & 3;
    const int fr = lane & 15;
    const int hi = lane >> 4;
    const int fsw = fr & 7;

    // grid 512: xcd = blk&7 owns bm {2*xcd, 2*xcd+1}; bn = local&31 fastest.
    const int local = blockIdx.x >> 3;              // 0..63
    const int bn0 = (local & 31) * 128;
    const int bm0 = ((blockIdx.x & 7) * 2 + (local >> 5)) * 128;

    const int srow = tid >> 3;
    const int sslot = tid & 7;
    const int gcol = (sslot ^ (srow & 7)) * 8;
    const unsigned short* Ag = A + (size_t)(bm0 + srow) * KA2 + gcol;
    const unsigned short* Bg = B + (size_t)(bn0 + srow) * KA2 + gcol;
    const size_t half = (size_t)64 * KA2;

    f32x4 acc[4][2] = {};

    for (int kt = 0; kt < KA2; kt += 64) {
        gload_lds16(Ag + kt,        &As[srow][sslot * 8]);
        gload_lds16(Ag + half + kt, &As[64 + srow][sslot * 8]);
        gload_lds16(Bg + kt,        &Bs[srow][sslot * 8]);
        gload_lds16(Bg + half + kt, &Bs[64 + srow][sslot * 8]);
        __syncthreads();
        #pragma unroll
        for (int kk = 0; kk < 2; ++kk) {
            bf16x8 a_[4], b_[2];
            #pragma unroll
            for (int m = 0; m < 4; ++m)
                a_[m] = *reinterpret_cast<const bf16x8*>(
                    &As[wr * 64 + m * 16 + fr][((kk * 4 + hi) ^ fsw) * 8]);
            #pragma unroll
            for (int n = 0; n < 2; ++n)
                b_[n] = *reinterpret_cast<const bf16x8*>(
                    &Bs[wc * 32 + n * 16 + fr][((kk * 4 + hi) ^ fsw) * 8]);
            #pragma unroll
            for (int m = 0; m < 4; ++m)
                #pragma unroll
                for (int n = 0; n < 2; ++n)
                    acc[m][n] = __builtin_amdgcn_mfma_f32_16x16x32_bf16(
                        a_[m], b_[n], acc[m][n], 0, 0, 0);
        }
        __syncthreads();
    }

    const int orow0 = bm0 + wr * 64 + hi * 4;
    const int ocol0 = bn0 + wc * 32 + fr;
    #pragma unroll
    for (int m = 0; m < 4; ++m)
        #pragma unroll
        for (int j = 0; j < 4; ++j) {
            const int row = orow0 + m * 16 + j;
            #pragma unroll
            for (int n = 0; n < 2; ++n)
                out[(size_t)row * H_DIM + ocol0 + n * 16] = acc[m][n][j];
        }
}

// ---------------------------------------------------------------------------
extern "C" void kernel_launch(void* const* d_in, const int* in_sizes, int n_in,
                              void* d_out, int out_size, void* d_ws, size_t ws_size,
                              hipStream_t stream)
{
    const float* x       = (const float*)d_in[0];
    const float* gate_w  = (const float*)d_in[1];
    const float* up_w    = (const float*)d_in[2];
    const float* down_w  = (const float*)d_in[3];
    const float* gate_wa = (const float*)d_in[4];
    const float* gate_wb = (const float*)d_in[5];
    const float* up_wa   = (const float*)d_in[6];
    const float* up_wb   = (const float*)d_in[7];
    const float* down_wa = (const float*)d_in[8];
    const float* down_wb = (const float*)d_in[9];
    const int*   indices = (const int*)d_in[10];
    float* out = (float*)d_out;

    char* ws = (char*)d_ws;
    size_t off = 0;
    auto alloc = [&](size_t bytes) {
        char* p = ws + off;
        off += (bytes + 255) & ~(size_t)255;
        return p;
    };
    unsigned short* xa     = (unsigned short*)alloc((size_t)T_TOK * KA1 * 2);
    unsigned short* wg_aug = (unsigned short*)alloc((size_t)I_DIM * KA1 * 2);
    unsigned short* wu_aug = (unsigned short*)alloc((size_t)I_DIM * KA1 * 2);
    unsigned short* t_aug  = (unsigned short*)alloc((size_t)T_TOK * KA2 * 2);
    float* v_gate = (float*)alloc((size_t)T_TOK * R_LORA * 4);
    float* v_up   = (float*)alloc((size_t)T_TOK * R_LORA * 4);
    float* v_down = (float*)alloc((size_t)T_TOK * R_LORA * 4);
    unsigned short* wd_aug = wu_aug;   // reused after pass1

    lora_v_gu<<<T_TOK, 256, 0, stream>>>(x, gate_wa, up_wa, indices, v_gate, v_up);
    build_xa<<<T_TOK, 256, 0, stream>>>(x, v_gate, v_up, indices, xa);
    build_w_aug<<<I_DIM, 256, 0, stream>>>(gate_w, gate_wb, wg_aug,
                                           I_DIM, H_DIM, KA1, H_DIM, H_DIM + 128);
    build_w_aug<<<I_DIM, 256, 0, stream>>>(up_w, up_wb, wu_aug,
                                           I_DIM, H_DIM, KA1, H_DIM + 128, H_DIM);

    // fused gate+up -> t. grid 8 bm x 172 bn
    gemm_fused_gu<<<8 * (I_DIM / 64), 512, 0, stream>>>(xa, wg_aug, wu_aug, t_aug);

    lora_v_down_k<<<T_TOK, 256, 0, stream>>>(t_aug, down_wa, indices, v_down);
    fill_ta<<<T_TOK, 128, 0, stream>>>(v_down, indices, t_aug);
    build_w_aug<<<H_DIM, 256, 0, stream>>>(down_w, down_wb, wd_aug,
                                           H_DIM, I_DIM, KA2, I_DIM, -1);

    // down GEMM -> out (fp32), grid 512
    gemm_down<<<512, 512, 0, stream>>>(t_aug, wd_aug, out);

    (void)in_sizes; (void)n_in; (void)out_size; (void)ws_size;
}

// Round 7
// 1073.127 us; speedup vs baseline: 1.2978x; 1.2978x over previous
//
#include <hip/hip_runtime.h>
#include <hip/hip_bf16.h>
#include <cstdint>

// ---------------------------------------------------------------------------
// LlamaMlpWithLora: T=2048, H=4096, I=11008, A=8, R=16, scale=0.5
// R7: pass1/pass2 = R5-exact (known 427us / <425us). LoRA-v via thin MFMA
//     GEMMs instead of scalar reduction kernels (kills ~540MB L3 streaming).
//   xa   [T][4352]  = [x | 0.5*v_g slots | 0.5*v_u slots]
//   Wg^/Wu^ [I][4352], t^ [T][11136], Wd^ [H][11136]
// ---------------------------------------------------------------------------

#define T_TOK 2048
#define H_DIM 4096
#define I_DIM 11008
#define R_LORA 16
#define KA1 4352    // H + 128(gate) + 128(up)
#define KA2 11136   // I + 128(down)

typedef __bf16 bf16x8 __attribute__((ext_vector_type(8)));
typedef float f32x4 __attribute__((ext_vector_type(4)));

__device__ __forceinline__ float bf2f(unsigned short u) {
    union { unsigned int i; float f; } v;
    v.i = ((unsigned int)u) << 16;
    return v.f;
}
__device__ __forceinline__ unsigned short f2bf(float f) {
    __bf16 b = (__bf16)f;
    unsigned short u;
    __builtin_memcpy(&u, &b, 2);
    return u;
}
__device__ __forceinline__ void cvt8(const float* s, unsigned short* d) {
    float4 a = reinterpret_cast<const float4*>(s)[0];
    float4 b = reinterpret_cast<const float4*>(s)[1];
    uint4 o;
    o.x = (unsigned)f2bf(a.x) | ((unsigned)f2bf(a.y) << 16);
    o.y = (unsigned)f2bf(a.z) | ((unsigned)f2bf(a.w) << 16);
    o.z = (unsigned)f2bf(b.x) | ((unsigned)f2bf(b.y) << 16);
    o.w = (unsigned)f2bf(b.z) | ((unsigned)f2bf(b.w) << 16);
    *reinterpret_cast<uint4*>(d) = o;
}
__device__ __forceinline__ void gload_lds16(const void* g, void* l) {
    __builtin_amdgcn_global_load_lds(
        (const __attribute__((address_space(1))) void*)g,
        (__attribute__((address_space(3))) void*)l,
        16, 0, 0);
}

// ---------------- small kernels --------------------------------------------
// rows of f32 -> bf16 (contiguous rows)
__global__ __launch_bounds__(256) void cvt_rows(
    const float* __restrict__ src, unsigned short* __restrict__ dst, int K)
{
    const int row = blockIdx.x;
    const int tid = threadIdx.x;
    const float* s = src + (size_t)row * K;
    unsigned short* d = dst + (size_t)row * K;
    for (int k = tid * 8; k < K; k += 256 * 8) cvt8(s + k, d + k);
}

// x -> xa x-part (bf16, stride KA1)
__global__ __launch_bounds__(256) void build_xa_x(
    const float* __restrict__ x, unsigned short* __restrict__ xa)
{
    const int t = blockIdx.x;
    const int tid = threadIdx.x;
    const float* s = x + (size_t)t * H_DIM;
    unsigned short* d = xa + (size_t)t * KA1;
    for (int k = tid * 8; k < H_DIM; k += 2048) cvt8(s + k, d + k);
}

// scatter 0.5*v into xa aug slots (256 cols: gate block then up block)
__global__ __launch_bounds__(256) void fill_xa_aug(
    const float* __restrict__ V, const int* __restrict__ idx,
    unsigned short* __restrict__ xa)
{
    const int t = blockIdx.x;
    const int tid = threadIdx.x;
    const int a = (tid & 127) >> 4;
    const float val = (a == idx[t]) ? 0.5f * V[(size_t)t * 256 + tid] : 0.f;
    xa[(size_t)t * KA1 + H_DIM + tid] = f2bf(val);
}

// scatter 0.5*v_d into t_aug aug slots (128 cols)
__global__ __launch_bounds__(128) void fill_ta(
    const float* __restrict__ V, const int* __restrict__ idx,
    unsigned short* __restrict__ t_aug)
{
    const int t = blockIdx.x;
    const int tid = threadIdx.x;
    const int a = tid >> 4;
    const float val = (a == idx[t]) ? 0.5f * V[(size_t)t * 128 + tid] : 0.f;
    t_aug[(size_t)t * KA2 + I_DIM + tid] = f2bf(val);
}

// weight row -> bf16 + lora-B aug columns (+ optional zero range)
__global__ __launch_bounds__(256) void build_w_aug(
    const float* __restrict__ w, const float* __restrict__ wb,
    unsigned short* __restrict__ dst,
    int Nrows, int Ksrc, int Kdst, int self_off, int zero_off)
{
    const int c = blockIdx.x;
    const int tid = threadIdx.x;
    const float* src = w + (size_t)c * Ksrc;
    unsigned short* d = dst + (size_t)c * Kdst;
    for (int k = tid * 8; k < Ksrc; k += 256 * 8) cvt8(src + k, d + k);
    if (tid < 128) {
        const int a = tid >> 4, r = tid & 15;
        const float v = wb[(((size_t)a * Nrows) + c) * R_LORA + r];
        d[self_off + tid] = f2bf(v);
        if (zero_off >= 0) d[zero_off + tid] = 0;
    }
}

// ---------------- thin GEMM: V = A(bf16,lda) @ B(bf16,ldb)^T -> f32 --------
__global__ __launch_bounds__(512) void gemm_thin(
    const unsigned short* __restrict__ A, int lda,
    const unsigned short* __restrict__ B, int ldb,
    float* __restrict__ out, int N, int K)
{
    __shared__ __align__(16) unsigned short As[128][64];
    __shared__ __align__(16) unsigned short Bs[128][64];

    const int tid = threadIdx.x;
    const int lane = tid & 63;
    const int wid = tid >> 6;
    const int wr = wid >> 2;
    const int wc = wid & 3;
    const int fr = lane & 15;
    const int hi = lane >> 4;
    const int fsw = fr & 7;

    const int bm0 = blockIdx.y * 128;
    const int bn0 = blockIdx.x * 128;

    const int srow = tid >> 3;
    const int sslot = tid & 7;
    const int gcol = (sslot ^ (srow & 7)) * 8;
    const unsigned short* Ag = A + (size_t)(bm0 + srow) * lda + gcol;
    const unsigned short* Bg = B + (size_t)(bn0 + srow) * ldb + gcol;
    const size_t halfA = (size_t)64 * lda;
    const size_t halfB = (size_t)64 * ldb;

    f32x4 acc[4][2] = {};

    for (int kt = 0; kt < K; kt += 64) {
        gload_lds16(Ag + kt,         &As[srow][sslot * 8]);
        gload_lds16(Ag + halfA + kt, &As[64 + srow][sslot * 8]);
        gload_lds16(Bg + kt,         &Bs[srow][sslot * 8]);
        gload_lds16(Bg + halfB + kt, &Bs[64 + srow][sslot * 8]);
        __syncthreads();
        #pragma unroll
        for (int kk = 0; kk < 2; ++kk) {
            bf16x8 a_[4], b_[2];
            #pragma unroll
            for (int m = 0; m < 4; ++m)
                a_[m] = *reinterpret_cast<const bf16x8*>(
                    &As[wr * 64 + m * 16 + fr][((kk * 4 + hi) ^ fsw) * 8]);
            #pragma unroll
            for (int n = 0; n < 2; ++n)
                b_[n] = *reinterpret_cast<const bf16x8*>(
                    &Bs[wc * 32 + n * 16 + fr][((kk * 4 + hi) ^ fsw) * 8]);
            #pragma unroll
            for (int m = 0; m < 4; ++m)
                #pragma unroll
                for (int n = 0; n < 2; ++n)
                    acc[m][n] = __builtin_amdgcn_mfma_f32_16x16x32_bf16(
                        a_[m], b_[n], acc[m][n], 0, 0, 0);
        }
        __syncthreads();
    }

    const int orow0 = bm0 + wr * 64 + hi * 4;
    const int ocol0 = bn0 + wc * 32 + fr;
    #pragma unroll
    for (int m = 0; m < 4; ++m)
        #pragma unroll
        for (int j = 0; j < 4; ++j) {
            const int row = orow0 + m * 16 + j;
            #pragma unroll
            for (int n = 0; n < 2; ++n)
                out[(size_t)row * N + ocol0 + n * 16] = acc[m][n][j];
        }
}

// ---------------- pass 1: fused gate+up GEMM (R5-exact, 427us) -------------
__global__ __launch_bounds__(512) void gemm_fused_gu(
    const unsigned short* __restrict__ A,   // xa [T][KA1]
    const unsigned short* __restrict__ Bg,  // wg_aug [I][KA1]
    const unsigned short* __restrict__ Bu,  // wu_aug [I][KA1]
    unsigned short* __restrict__ Tout)      // t_aug [T][KA2]
{
    __shared__ __align__(16) unsigned short As[128][64];
    __shared__ __align__(16) unsigned short Bgs[128][64];
    __shared__ __align__(16) unsigned short Bus[128][64];

    const int tid = threadIdx.x;
    const int lane = tid & 63;
    const int wid = tid >> 6;
    const int wr = wid >> 2;           // 0..1
    const int wc = wid & 3;            // 0..3
    const int fr = lane & 15;
    const int hi = lane >> 4;
    const int fsw = fr & 7;

    const int nwg = gridDim.x;                                   // 1376
    const int swz = (blockIdx.x & 7) * (nwg >> 3) + (blockIdx.x >> 3);
    const int bm0 = (swz / 86) * 128;
    const int bn0 = (swz % 86) * 128;

    const int srow = tid >> 3;
    const int sslot = tid & 7;
    const int gcol = (sslot ^ (srow & 7)) * 8;
    const unsigned short* Ag  = A  + (size_t)(bm0 + srow) * KA1 + gcol;
    const unsigned short* Bgg = Bg + (size_t)(bn0 + srow) * KA1 + gcol;
    const unsigned short* Bug = Bu + (size_t)(bn0 + srow) * KA1 + gcol;
    const size_t half = (size_t)64 * KA1;

    f32x4 accg[4][2] = {};
    f32x4 accu[4][2] = {};

    for (int kt = 0; kt < KA1; kt += 64) {
        gload_lds16(Ag + kt,         &As[srow][sslot * 8]);
        gload_lds16(Ag + half + kt,  &As[64 + srow][sslot * 8]);
        gload_lds16(Bgg + kt,        &Bgs[srow][sslot * 8]);
        gload_lds16(Bgg + half + kt, &Bgs[64 + srow][sslot * 8]);
        gload_lds16(Bug + kt,        &Bus[srow][sslot * 8]);
        gload_lds16(Bug + half + kt, &Bus[64 + srow][sslot * 8]);
        __syncthreads();
        #pragma unroll
        for (int kk = 0; kk < 2; ++kk) {
            bf16x8 a_[4], bg_[2], bu_[2];
            #pragma unroll
            for (int m = 0; m < 4; ++m)
                a_[m] = *reinterpret_cast<const bf16x8*>(
                    &As[wr * 64 + m * 16 + fr][((kk * 4 + hi) ^ fsw) * 8]);
            #pragma unroll
            for (int n = 0; n < 2; ++n) {
                bg_[n] = *reinterpret_cast<const bf16x8*>(
                    &Bgs[wc * 32 + n * 16 + fr][((kk * 4 + hi) ^ fsw) * 8]);
                bu_[n] = *reinterpret_cast<const bf16x8*>(
                    &Bus[wc * 32 + n * 16 + fr][((kk * 4 + hi) ^ fsw) * 8]);
            }
            #pragma unroll
            for (int m = 0; m < 4; ++m)
                #pragma unroll
                for (int n = 0; n < 2; ++n) {
                    accg[m][n] = __builtin_amdgcn_mfma_f32_16x16x32_bf16(
                        a_[m], bg_[n], accg[m][n], 0, 0, 0);
                    accu[m][n] = __builtin_amdgcn_mfma_f32_16x16x32_bf16(
                        a_[m], bu_[n], accu[m][n], 0, 0, 0);
                }
        }
        __syncthreads();
    }

    const int orow0 = bm0 + wr * 64 + hi * 4;
    const int ocol0 = bn0 + wc * 32 + fr;
    #pragma unroll
    for (int m = 0; m < 4; ++m)
        #pragma unroll
        for (int j = 0; j < 4; ++j) {
            const int row = orow0 + m * 16 + j;
            #pragma unroll
            for (int n = 0; n < 2; ++n) {
                const float g = accg[m][n][j];
                const float u = accu[m][n][j];
                const float sg = g / (1.f + __expf(-g));
                Tout[(size_t)row * KA2 + ocol0 + n * 16] = f2bf(sg * u);
            }
        }
}

// ---------------- pass 2: down GEMM (R5-exact) -----------------------------
__global__ __launch_bounds__(512) void gemm_down(
    const unsigned short* __restrict__ A,   // t_aug [T][KA2]
    const unsigned short* __restrict__ B,   // wd_aug [H][KA2]
    float* __restrict__ out)                // [T][H]
{
    __shared__ __align__(16) unsigned short As[128][64];
    __shared__ __align__(16) unsigned short Bs[128][64];

    const int tid = threadIdx.x;
    const int lane = tid & 63;
    const int wid = tid >> 6;
    const int wr = wid >> 2;
    const int wc = wid & 3;
    const int fr = lane & 15;
    const int hi = lane >> 4;
    const int fsw = fr & 7;

    const int nwg = gridDim.x;                                   // 512
    const int swz = (blockIdx.x & 7) * (nwg >> 3) + (blockIdx.x >> 3);
    const int bm0 = (swz / 32) * 128;
    const int bn0 = (swz % 32) * 128;

    const int srow = tid >> 3;
    const int sslot = tid & 7;
    const int gcol = (sslot ^ (srow & 7)) * 8;
    const unsigned short* Ag = A + (size_t)(bm0 + srow) * KA2 + gcol;
    const unsigned short* Bg = B + (size_t)(bn0 + srow) * KA2 + gcol;
    const size_t half = (size_t)64 * KA2;

    f32x4 acc[4][2] = {};

    for (int kt = 0; kt < KA2; kt += 64) {
        gload_lds16(Ag + kt,        &As[srow][sslot * 8]);
        gload_lds16(Ag + half + kt, &As[64 + srow][sslot * 8]);
        gload_lds16(Bg + kt,        &Bs[srow][sslot * 8]);
        gload_lds16(Bg + half + kt, &Bs[64 + srow][sslot * 8]);
        __syncthreads();
        #pragma unroll
        for (int kk = 0; kk < 2; ++kk) {
            bf16x8 a_[4], b_[2];
            #pragma unroll
            for (int m = 0; m < 4; ++m)
                a_[m] = *reinterpret_cast<const bf16x8*>(
                    &As[wr * 64 + m * 16 + fr][((kk * 4 + hi) ^ fsw) * 8]);
            #pragma unroll
            for (int n = 0; n < 2; ++n)
                b_[n] = *reinterpret_cast<const bf16x8*>(
                    &Bs[wc * 32 + n * 16 + fr][((kk * 4 + hi) ^ fsw) * 8]);
            #pragma unroll
            for (int m = 0; m < 4; ++m)
                #pragma unroll
                for (int n = 0; n < 2; ++n)
                    acc[m][n] = __builtin_amdgcn_mfma_f32_16x16x32_bf16(
                        a_[m], b_[n], acc[m][n], 0, 0, 0);
        }
        __syncthreads();
    }

    const int orow0 = bm0 + wr * 64 + hi * 4;
    const int ocol0 = bn0 + wc * 32 + fr;
    #pragma unroll
    for (int m = 0; m < 4; ++m)
        #pragma unroll
        for (int j = 0; j < 4; ++j) {
            const int row = orow0 + m * 16 + j;
            #pragma unroll
            for (int n = 0; n < 2; ++n)
                out[(size_t)row * H_DIM + ocol0 + n * 16] = acc[m][n][j];
        }
}

// ---------------------------------------------------------------------------
extern "C" void kernel_launch(void* const* d_in, const int* in_sizes, int n_in,
                              void* d_out, int out_size, void* d_ws, size_t ws_size,
                              hipStream_t stream)
{
    const float* x       = (const float*)d_in[0];
    const float* gate_w  = (const float*)d_in[1];
    const float* up_w    = (const float*)d_in[2];
    const float* down_w  = (const float*)d_in[3];
    const float* gate_wa = (const float*)d_in[4];
    const float* gate_wb = (const float*)d_in[5];
    const float* up_wa   = (const float*)d_in[6];
    const float* up_wb   = (const float*)d_in[7];
    const float* down_wa = (const float*)d_in[8];
    const float* down_wb = (const float*)d_in[9];
    const int*   indices = (const int*)d_in[10];
    float* out = (float*)d_out;

    char* ws = (char*)d_ws;
    size_t off = 0;
    auto alloc = [&](size_t bytes) {
        char* p = ws + off;
        off += (bytes + 255) & ~(size_t)255;
        return p;
    };
    unsigned short* xa     = (unsigned short*)alloc((size_t)T_TOK * KA1 * 2);
    unsigned short* wg_aug = (unsigned short*)alloc((size_t)I_DIM * KA1 * 2);
    unsigned short* wu_aug = (unsigned short*)alloc((size_t)I_DIM * KA1 * 2);
    unsigned short* t_aug  = (unsigned short*)alloc((size_t)T_TOK * KA2 * 2);
    unsigned short* wab_gu = (unsigned short*)alloc((size_t)256 * H_DIM * 2); // 2MB
    // overlays (dead-range reuse, no extra ws):
    float* Vgu = (float*)t_aug;                     // 2MB, dead before pass1 writes t_aug
    float* Vd  = (float*)wab_gu;                    // 1MB, wab_gu dead post-pass1
    unsigned short* wd_aug = wu_aug;                // reused after pass1
    unsigned short* wab_d  = wu_aug + (size_t)H_DIM * KA2;  // tail of wu slot (4.5MB free)

    // --- LoRA-A projections via thin GEMMs ---
    cvt_rows<<<128, 256, 0, stream>>>(gate_wa, wab_gu, H_DIM);
    cvt_rows<<<128, 256, 0, stream>>>(up_wa, wab_gu + (size_t)128 * H_DIM, H_DIM);
    build_xa_x<<<T_TOK, 256, 0, stream>>>(x, xa);
    gemm_thin<<<dim3(2, 16), 512, 0, stream>>>(xa, KA1, wab_gu, H_DIM, Vgu, 256, H_DIM);
    fill_xa_aug<<<T_TOK, 256, 0, stream>>>(Vgu, indices, xa);

    // --- augmented weights ---
    build_w_aug<<<I_DIM, 256, 0, stream>>>(gate_w, gate_wb, wg_aug,
                                           I_DIM, H_DIM, KA1, H_DIM, H_DIM + 128);
    build_w_aug<<<I_DIM, 256, 0, stream>>>(up_w, up_wb, wu_aug,
                                           I_DIM, H_DIM, KA1, H_DIM + 128, H_DIM);

    // --- pass 1: fused gate+up -> t ---
    gemm_fused_gu<<<16 * 86, 512, 0, stream>>>(xa, wg_aug, wu_aug, t_aug);

    // --- down LoRA + weights ---
    cvt_rows<<<128, 256, 0, stream>>>(down_wa, wab_d, I_DIM);
    gemm_thin<<<dim3(1, 16), 512, 0, stream>>>(t_aug, KA2, wab_d, I_DIM, Vd, 128, I_DIM);
    fill_ta<<<T_TOK, 128, 0, stream>>>(Vd, indices, t_aug);
    build_w_aug<<<H_DIM, 256, 0, stream>>>(down_w, down_wb, wd_aug,
                                           H_DIM, I_DIM, KA2, I_DIM, -1);

    // --- pass 2: down -> out ---
    gemm_down<<<512, 512, 0, stream>>>(t_aug, wd_aug, out);

    (void)in_sizes; (void)n_in; (void)out_size; (void)ws_size;
}

// Round 8
// 1004.425 us; speedup vs baseline: 1.3866x; 1.0684x over previous
//
#include <hip/hip_runtime.h>
#include <hip/hip_bf16.h>
#include <cstdint>

// ---------------------------------------------------------------------------
// LlamaMlpWithLora: T=2048, H=4096, I=11008, A=8, R=16, scale=0.5
// R8: counted-vmcnt pipelined GEMMs (T3/T4/T5) with derived waits.
//   pass1: BM=256 BN=128 fused gate+up, 2-buf, P0{A,Bg}/P1{Bu} phases,
//          waits vmcnt(6)@P0, vmcnt(2)@P1 (never 0 in steady state).
//   pass2: BM=256 BN=128 down, 3-buf, 2-tile-deep prefetch, vmcnt(6)@P1.
//   LoRA folded into K (augmented operands), thin-GEMM LoRA projections.
// ---------------------------------------------------------------------------

#define T_TOK 2048
#define H_DIM 4096
#define I_DIM 11008
#define R_LORA 16
#define KA1 4352    // H + 128(gate) + 128(up)
#define KA2 11136   // I + 128(down)

typedef __bf16 bf16x8 __attribute__((ext_vector_type(8)));
typedef float f32x4 __attribute__((ext_vector_type(4)));

__device__ __forceinline__ float bf2f(unsigned short u) {
    union { unsigned int i; float f; } v;
    v.i = ((unsigned int)u) << 16;
    return v.f;
}
__device__ __forceinline__ unsigned short f2bf(float f) {
    __bf16 b = (__bf16)f;
    unsigned short u;
    __builtin_memcpy(&u, &b, 2);
    return u;
}
__device__ __forceinline__ void cvt8(const float* s, unsigned short* d) {
    float4 a = reinterpret_cast<const float4*>(s)[0];
    float4 b = reinterpret_cast<const float4*>(s)[1];
    uint4 o;
    o.x = (unsigned)f2bf(a.x) | ((unsigned)f2bf(a.y) << 16);
    o.y = (unsigned)f2bf(a.z) | ((unsigned)f2bf(a.w) << 16);
    o.z = (unsigned)f2bf(b.x) | ((unsigned)f2bf(b.y) << 16);
    o.w = (unsigned)f2bf(b.z) | ((unsigned)f2bf(b.w) << 16);
    *reinterpret_cast<uint4*>(d) = o;
}
__device__ __forceinline__ void gload_lds16(const void* g, void* l) {
    __builtin_amdgcn_global_load_lds(
        (const __attribute__((address_space(1))) void*)g,
        (__attribute__((address_space(3))) void*)l,
        16, 0, 0);
}

// ---------------- small kernels --------------------------------------------
__global__ __launch_bounds__(256) void cvt_rows(
    const float* __restrict__ src, unsigned short* __restrict__ dst, int K)
{
    const int row = blockIdx.x;
    const int tid = threadIdx.x;
    const float* s = src + (size_t)row * K;
    unsigned short* d = dst + (size_t)row * K;
    for (int k = tid * 8; k < K; k += 256 * 8) cvt8(s + k, d + k);
}

__global__ __launch_bounds__(256) void build_xa_x(
    const float* __restrict__ x, unsigned short* __restrict__ xa)
{
    const int t = blockIdx.x;
    const int tid = threadIdx.x;
    const float* s = x + (size_t)t * H_DIM;
    unsigned short* d = xa + (size_t)t * KA1;
    for (int k = tid * 8; k < H_DIM; k += 2048) cvt8(s + k, d + k);
}

__global__ __launch_bounds__(256) void fill_xa_aug(
    const float* __restrict__ V, const int* __restrict__ idx,
    unsigned short* __restrict__ xa)
{
    const int t = blockIdx.x;
    const int tid = threadIdx.x;
    const int a = (tid & 127) >> 4;
    const float val = (a == idx[t]) ? 0.5f * V[(size_t)t * 256 + tid] : 0.f;
    xa[(size_t)t * KA1 + H_DIM + tid] = f2bf(val);
}

__global__ __launch_bounds__(128) void fill_ta(
    const float* __restrict__ V, const int* __restrict__ idx,
    unsigned short* __restrict__ t_aug)
{
    const int t = blockIdx.x;
    const int tid = threadIdx.x;
    const int a = tid >> 4;
    const float val = (a == idx[t]) ? 0.5f * V[(size_t)t * 128 + tid] : 0.f;
    t_aug[(size_t)t * KA2 + I_DIM + tid] = f2bf(val);
}

__global__ __launch_bounds__(256) void build_w_aug(
    const float* __restrict__ w, const float* __restrict__ wb,
    unsigned short* __restrict__ dst,
    int Nrows, int Ksrc, int Kdst, int self_off, int zero_off)
{
    const int c = blockIdx.x;
    const int tid = threadIdx.x;
    const float* src = w + (size_t)c * Ksrc;
    unsigned short* d = dst + (size_t)c * Kdst;
    for (int k = tid * 8; k < Ksrc; k += 256 * 8) cvt8(src + k, d + k);
    if (tid < 128) {
        const int a = tid >> 4, r = tid & 15;
        const float v = wb[(((size_t)a * Nrows) + c) * R_LORA + r];
        d[self_off + tid] = f2bf(v);
        if (zero_off >= 0) d[zero_off + tid] = 0;
    }
}

// ---------------- thin GEMM (R7-exact) -------------------------------------
__global__ __launch_bounds__(512) void gemm_thin(
    const unsigned short* __restrict__ A, int lda,
    const unsigned short* __restrict__ B, int ldb,
    float* __restrict__ out, int N, int K)
{
    __shared__ __align__(16) unsigned short As[128][64];
    __shared__ __align__(16) unsigned short Bs[128][64];

    const int tid = threadIdx.x;
    const int lane = tid & 63;
    const int wid = tid >> 6;
    const int wr = wid >> 2;
    const int wc = wid & 3;
    const int fr = lane & 15;
    const int hi = lane >> 4;
    const int fsw = fr & 7;

    const int bm0 = blockIdx.y * 128;
    const int bn0 = blockIdx.x * 128;

    const int srow = tid >> 3;
    const int sslot = tid & 7;
    const int gcol = (sslot ^ (srow & 7)) * 8;
    const unsigned short* Ag = A + (size_t)(bm0 + srow) * lda + gcol;
    const unsigned short* Bg = B + (size_t)(bn0 + srow) * ldb + gcol;
    const size_t halfA = (size_t)64 * lda;
    const size_t halfB = (size_t)64 * ldb;

    f32x4 acc[4][2] = {};

    for (int kt = 0; kt < K; kt += 64) {
        gload_lds16(Ag + kt,         &As[srow][sslot * 8]);
        gload_lds16(Ag + halfA + kt, &As[64 + srow][sslot * 8]);
        gload_lds16(Bg + kt,         &Bs[srow][sslot * 8]);
        gload_lds16(Bg + halfB + kt, &Bs[64 + srow][sslot * 8]);
        __syncthreads();
        #pragma unroll
        for (int kk = 0; kk < 2; ++kk) {
            bf16x8 a_[4], b_[2];
            #pragma unroll
            for (int m = 0; m < 4; ++m)
                a_[m] = *reinterpret_cast<const bf16x8*>(
                    &As[wr * 64 + m * 16 + fr][((kk * 4 + hi) ^ fsw) * 8]);
            #pragma unroll
            for (int n = 0; n < 2; ++n)
                b_[n] = *reinterpret_cast<const bf16x8*>(
                    &Bs[wc * 32 + n * 16 + fr][((kk * 4 + hi) ^ fsw) * 8]);
            #pragma unroll
            for (int m = 0; m < 4; ++m)
                #pragma unroll
                for (int n = 0; n < 2; ++n)
                    acc[m][n] = __builtin_amdgcn_mfma_f32_16x16x32_bf16(
                        a_[m], b_[n], acc[m][n], 0, 0, 0);
        }
        __syncthreads();
    }

    const int orow0 = bm0 + wr * 64 + hi * 4;
    const int ocol0 = bn0 + wc * 32 + fr;
    #pragma unroll
    for (int m = 0; m < 4; ++m)
        #pragma unroll
        for (int j = 0; j < 4; ++j) {
            const int row = orow0 + m * 16 + j;
            #pragma unroll
            for (int n = 0; n < 2; ++n)
                out[(size_t)row * N + ocol0 + n * 16] = acc[m][n][j];
        }
}

// ---------------- pass 1: fused gate+up, counted-vmcnt pipeline ------------
// BM=256, BN=128, BK=64. 8 waves 4Mx2N, per-wave 64x64 per matrix.
// LDS rows: A 0-255, Bg 256-383, Bu 384-511. 2 buffers, 64KB each.
// Units (8KB, all-waves): A0-3, Bg0-1 (issued @P0), Bu0-1 (issued @P1).
// Waits: P0 vmcnt(6) [protects P1's Bu], P1 vmcnt(2) [protects next P0's A+Bg].
__global__ __launch_bounds__(512, 2) void gemm_fused_gu(
    const unsigned short* __restrict__ A,
    const unsigned short* __restrict__ Bg,
    const unsigned short* __restrict__ Bu,
    unsigned short* __restrict__ Tout)
{
    __shared__ __align__(16) unsigned short lds[2][512][64];

    const int tid = threadIdx.x;
    const int lane = tid & 63;
    const int wid = tid >> 6;
    const int wr = wid >> 1;           // 0..3 (M quarter, 64 rows)
    const int wc = wid & 1;            // 0..1 (N half, 64 cols)
    const int fr = lane & 15;
    const int hi = lane >> 4;
    const int fsw = fr & 7;

    const int bm0 = (blockIdx.x & 7) * 256;   // XCD-pinned A-slab (2.2MB, L2)
    const int bn0 = (blockIdx.x >> 3) * 128;

    const int srow = tid >> 3;
    const int sslot = tid & 7;
    const int gcol = (sslot ^ (srow & 7)) * 8;
    const unsigned short* Ap  = A  + (size_t)(bm0 + srow) * KA1 + gcol;
    const unsigned short* Bgp = Bg + (size_t)(bn0 + srow) * KA1 + gcol;
    const unsigned short* Bup = Bu + (size_t)(bn0 + srow) * KA1 + gcol;

    f32x4 accg[4][4] = {};
    f32x4 accu[4][4] = {};

    const int nt = KA1 / 64;   // 68
    int cur = 0;

    auto stage_AB = [&](int buf, int kt) {
        #pragma unroll
        for (int q = 0; q < 4; ++q)
            gload_lds16(Ap + (size_t)(q * 64) * KA1 + kt, &lds[buf][q * 64 + srow][sslot * 8]);
        gload_lds16(Bgp + kt,                      &lds[buf][256 + srow][sslot * 8]);
        gload_lds16(Bgp + (size_t)64 * KA1 + kt,   &lds[buf][320 + srow][sslot * 8]);
    };
    auto stage_U = [&](int buf, int kt) {
        gload_lds16(Bup + kt,                      &lds[buf][384 + srow][sslot * 8]);
        gload_lds16(Bup + (size_t)64 * KA1 + kt,   &lds[buf][448 + srow][sslot * 8]);
    };

    // prologue: tile 0 fully staged; retire A+Bg (keep Bu in flight)
    stage_AB(0, 0);
    stage_U(0, 0);
    asm volatile("s_waitcnt vmcnt(2)" ::: "memory");
    __builtin_amdgcn_s_barrier();

    for (int t = 0; t < nt; ++t) {
        const int nxt = cur ^ 1;
        const bool last = (t == nt - 1);
        const int ktn = (t + 1) * 64;

        // ---- P0: gate ----
        bf16x8 a_[4][2], b_[4][2];
        #pragma unroll
        for (int m = 0; m < 4; ++m)
            #pragma unroll
            for (int k = 0; k < 2; ++k)
                a_[m][k] = *reinterpret_cast<const bf16x8*>(
                    &lds[cur][wr * 64 + m * 16 + fr][((k * 4 + hi) ^ fsw) * 8]);
        #pragma unroll
        for (int n = 0; n < 4; ++n)
            #pragma unroll
            for (int k = 0; k < 2; ++k)
                b_[n][k] = *reinterpret_cast<const bf16x8*>(
                    &lds[cur][256 + wc * 64 + n * 16 + fr][((k * 4 + hi) ^ fsw) * 8]);
        if (!last) stage_AB(nxt, ktn);
        if (last) asm volatile("s_waitcnt vmcnt(0)" ::: "memory");
        else      asm volatile("s_waitcnt vmcnt(6)" ::: "memory");
        __builtin_amdgcn_s_barrier();
        asm volatile("s_waitcnt lgkmcnt(0)" ::: "memory");
        __builtin_amdgcn_sched_barrier(0);
        __builtin_amdgcn_s_setprio(1);
        #pragma unroll
        for (int m = 0; m < 4; ++m)
            #pragma unroll
            for (int n = 0; n < 4; ++n)
                #pragma unroll
                for (int k = 0; k < 2; ++k)
                    accg[m][n] = __builtin_amdgcn_mfma_f32_16x16x32_bf16(
                        a_[m][k], b_[n][k], accg[m][n], 0, 0, 0);
        __builtin_amdgcn_s_setprio(0);
        __builtin_amdgcn_s_barrier();

        // ---- P1: up ----
        #pragma unroll
        for (int n = 0; n < 4; ++n)
            #pragma unroll
            for (int k = 0; k < 2; ++k)
                b_[n][k] = *reinterpret_cast<const bf16x8*>(
                    &lds[cur][384 + wc * 64 + n * 16 + fr][((k * 4 + hi) ^ fsw) * 8]);
        if (!last) stage_U(nxt, ktn);
        if (!last) asm volatile("s_waitcnt vmcnt(2)" ::: "memory");
        __builtin_amdgcn_s_barrier();
        asm volatile("s_waitcnt lgkmcnt(0)" ::: "memory");
        __builtin_amdgcn_sched_barrier(0);
        __builtin_amdgcn_s_setprio(1);
        #pragma unroll
        for (int m = 0; m < 4; ++m)
            #pragma unroll
            for (int n = 0; n < 4; ++n)
                #pragma unroll
                for (int k = 0; k < 2; ++k)
                    accu[m][n] = __builtin_amdgcn_mfma_f32_16x16x32_bf16(
                        a_[m][k], b_[n][k], accu[m][n], 0, 0, 0);
        __builtin_amdgcn_s_setprio(0);
        __builtin_amdgcn_s_barrier();

        cur = nxt;
    }

    const int orow0 = bm0 + wr * 64 + hi * 4;
    const int ocol0 = bn0 + wc * 64 + fr;
    #pragma unroll
    for (int m = 0; m < 4; ++m)
        #pragma unroll
        for (int j = 0; j < 4; ++j) {
            const int row = orow0 + m * 16 + j;
            #pragma unroll
            for (int n = 0; n < 4; ++n) {
                const float g = accg[m][n][j];
                const float u = accu[m][n][j];
                const float sg = g / (1.f + __expf(-g));
                Tout[(size_t)row * KA2 + ocol0 + n * 16] = f2bf(sg * u);
            }
        }
}

// ---------------- pass 2: down, 3-buffer 2-deep pipeline -------------------
// BM=256, BN=128. LDS rows: A 0-255, B 256-383; 3 buffers (144KB).
// Units: A0-3 (@P0), B0-1 (@P1) of tile t+2 staged during tile t.
// Single wait vmcnt(6) @P1 (vmcnt(0) at t==nt-2).
__global__ __launch_bounds__(512, 2) void gemm_down(
    const unsigned short* __restrict__ A,
    const unsigned short* __restrict__ B,
    float* __restrict__ out)
{
    __shared__ __align__(16) unsigned short lds[3][384][64];

    const int tid = threadIdx.x;
    const int lane = tid & 63;
    const int wid = tid >> 6;
    const int wr = wid >> 1;           // 0..3
    const int wc = wid & 1;            // 0..1
    const int fr = lane & 15;
    const int hi = lane >> 4;
    const int fsw = fr & 7;

    const int bm0 = (blockIdx.x & 7) * 256;
    const int bn0 = (blockIdx.x >> 3) * 128;

    const int srow = tid >> 3;
    const int sslot = tid & 7;
    const int gcol = (sslot ^ (srow & 7)) * 8;
    const unsigned short* Ap = A + (size_t)(bm0 + srow) * KA2 + gcol;
    const unsigned short* Bp = B + (size_t)(bn0 + srow) * KA2 + gcol;

    f32x4 acc[4][4] = {};

    const int nt = KA2 / 64;   // 174
    int cur = 0, st = 2;

    auto stage_A = [&](int buf, int kt) {
        #pragma unroll
        for (int q = 0; q < 4; ++q)
            gload_lds16(Ap + (size_t)(q * 64) * KA2 + kt, &lds[buf][q * 64 + srow][sslot * 8]);
    };
    auto stage_B = [&](int buf, int kt) {
        gload_lds16(Bp + kt,                     &lds[buf][256 + srow][sslot * 8]);
        gload_lds16(Bp + (size_t)64 * KA2 + kt,  &lds[buf][320 + srow][sslot * 8]);
    };

    // prologue: tiles 0 and 1 staged; retire tile 0 (keep tile 1 in flight)
    stage_A(0, 0);  stage_B(0, 0);
    stage_A(1, 64); stage_B(1, 64);
    asm volatile("s_waitcnt vmcnt(6)" ::: "memory");
    __builtin_amdgcn_s_barrier();

    for (int t = 0; t < nt; ++t) {
        const bool has2 = (t + 2 < nt);
        const int ktn = (t + 2) * 64;

        // ---- P0 ----
        bf16x8 a_[4][2], b_[4][2];
        #pragma unroll
        for (int m = 0; m < 4; ++m)
            #pragma unroll
            for (int k = 0; k < 2; ++k)
                a_[m][k] = *reinterpret_cast<const bf16x8*>(
                    &lds[cur][wr * 64 + m * 16 + fr][((k * 4 + hi) ^ fsw) * 8]);
        #pragma unroll
        for (int n = 0; n < 2; ++n)
            #pragma unroll
            for (int k = 0; k < 2; ++k)
                b_[n][k] = *reinterpret_cast<const bf16x8*>(
                    &lds[cur][256 + wc * 64 + n * 16 + fr][((k * 4 + hi) ^ fsw) * 8]);
        if (has2) stage_A(st, ktn);
        __builtin_amdgcn_s_barrier();
        asm volatile("s_waitcnt lgkmcnt(0)" ::: "memory");
        __builtin_amdgcn_sched_barrier(0);
        __builtin_amdgcn_s_setprio(1);
        #pragma unroll
        for (int m = 0; m < 4; ++m)
            #pragma unroll
            for (int n = 0; n < 2; ++n)
                #pragma unroll
                for (int k = 0; k < 2; ++k)
                    acc[m][n] = __builtin_amdgcn_mfma_f32_16x16x32_bf16(
                        a_[m][k], b_[n][k], acc[m][n], 0, 0, 0);
        __builtin_amdgcn_s_setprio(0);
        __builtin_amdgcn_s_barrier();

        // ---- P1 ----
        #pragma unroll
        for (int n = 0; n < 2; ++n)
            #pragma unroll
            for (int k = 0; k < 2; ++k)
                b_[n][k] = *reinterpret_cast<const bf16x8*>(
                    &lds[cur][256 + wc * 64 + (n + 2) * 16 + fr][((k * 4 + hi) ^ fsw) * 8]);
        if (has2) stage_B(st, ktn);
        if (t == nt - 2) asm volatile("s_waitcnt vmcnt(0)" ::: "memory");
        else if (t < nt - 2) asm volatile("s_waitcnt vmcnt(6)" ::: "memory");
        __builtin_amdgcn_s_barrier();
        asm volatile("s_waitcnt lgkmcnt(0)" ::: "memory");
        __builtin_amdgcn_sched_barrier(0);
        __builtin_amdgcn_s_setprio(1);
        #pragma unroll
        for (int m = 0; m < 4; ++m)
            #pragma unroll
            for (int n = 0; n < 2; ++n)
                #pragma unroll
                for (int k = 0; k < 2; ++k)
                    acc[m][n + 2] = __builtin_amdgcn_mfma_f32_16x16x32_bf16(
                        a_[m][k], b_[n][k], acc[m][n + 2], 0, 0, 0);
        __builtin_amdgcn_s_setprio(0);
        __builtin_amdgcn_s_barrier();

        cur = (cur == 2) ? 0 : cur + 1;
        st  = (st == 2) ? 0 : st + 1;
    }

    const int orow0 = bm0 + wr * 64 + hi * 4;
    const int ocol0 = bn0 + wc * 64 + fr;
    #pragma unroll
    for (int m = 0; m < 4; ++m)
        #pragma unroll
        for (int j = 0; j < 4; ++j) {
            const int row = orow0 + m * 16 + j;
            #pragma unroll
            for (int n = 0; n < 4; ++n)
                out[(size_t)row * H_DIM + ocol0 + n * 16] = acc[m][n][j];
        }
}

// ---------------------------------------------------------------------------
extern "C" void kernel_launch(void* const* d_in, const int* in_sizes, int n_in,
                              void* d_out, int out_size, void* d_ws, size_t ws_size,
                              hipStream_t stream)
{
    const float* x       = (const float*)d_in[0];
    const float* gate_w  = (const float*)d_in[1];
    const float* up_w    = (const float*)d_in[2];
    const float* down_w  = (const float*)d_in[3];
    const float* gate_wa = (const float*)d_in[4];
    const float* gate_wb = (const float*)d_in[5];
    const float* up_wa   = (const float*)d_in[6];
    const float* up_wb   = (const float*)d_in[7];
    const float* down_wa = (const float*)d_in[8];
    const float* down_wb = (const float*)d_in[9];
    const int*   indices = (const int*)d_in[10];
    float* out = (float*)d_out;

    char* ws = (char*)d_ws;
    size_t off = 0;
    auto alloc = [&](size_t bytes) {
        char* p = ws + off;
        off += (bytes + 255) & ~(size_t)255;
        return p;
    };
    unsigned short* xa     = (unsigned short*)alloc((size_t)T_TOK * KA1 * 2);
    unsigned short* wg_aug = (unsigned short*)alloc((size_t)I_DIM * KA1 * 2);
    unsigned short* wu_aug = (unsigned short*)alloc((size_t)I_DIM * KA1 * 2);
    unsigned short* t_aug  = (unsigned short*)alloc((size_t)T_TOK * KA2 * 2);
    unsigned short* wab_gu = (unsigned short*)alloc((size_t)256 * H_DIM * 2);
    float* Vgu = (float*)t_aug;                     // overlay, dead before pass1
    float* Vd  = (float*)wab_gu;                    // overlay, dead post-pass1
    unsigned short* wd_aug = wu_aug;                // reused after pass1
    unsigned short* wab_d  = wu_aug + (size_t)H_DIM * KA2;  // tail of wu slot

    // --- LoRA-A projections via thin GEMMs ---
    cvt_rows<<<128, 256, 0, stream>>>(gate_wa, wab_gu, H_DIM);
    cvt_rows<<<128, 256, 0, stream>>>(up_wa, wab_gu + (size_t)128 * H_DIM, H_DIM);
    build_xa_x<<<T_TOK, 256, 0, stream>>>(x, xa);
    gemm_thin<<<dim3(2, 16), 512, 0, stream>>>(xa, KA1, wab_gu, H_DIM, Vgu, 256, H_DIM);
    fill_xa_aug<<<T_TOK, 256, 0, stream>>>(Vgu, indices, xa);

    // --- augmented weights ---
    build_w_aug<<<I_DIM, 256, 0, stream>>>(gate_w, gate_wb, wg_aug,
                                           I_DIM, H_DIM, KA1, H_DIM, H_DIM + 128);
    build_w_aug<<<I_DIM, 256, 0, stream>>>(up_w, up_wb, wu_aug,
                                           I_DIM, H_DIM, KA1, H_DIM + 128, H_DIM);

    // --- pass 1: fused gate+up -> t. grid 8 bm x 86 bn ---
    gemm_fused_gu<<<8 * (I_DIM / 128), 512, 0, stream>>>(xa, wg_aug, wu_aug, t_aug);

    // --- down LoRA + weights ---
    cvt_rows<<<128, 256, 0, stream>>>(down_wa, wab_d, I_DIM);
    gemm_thin<<<dim3(1, 16), 512, 0, stream>>>(t_aug, KA2, wab_d, I_DIM, Vd, 128, I_DIM);
    fill_ta<<<T_TOK, 128, 0, stream>>>(Vd, indices, t_aug);
    build_w_aug<<<H_DIM, 256, 0, stream>>>(down_w, down_wb, wd_aug,
                                           H_DIM, I_DIM, KA2, I_DIM, -1);

    // --- pass 2: down -> out. grid 8 bm x 32 bn = 256 (perfect fill) ---
    gemm_down<<<8 * (H_DIM / 128), 512, 0, stream>>>(t_aug, wd_aug, out);

    (void)in_sizes; (void)n_in; (void)out_size; (void)ws_size;
}

// Round 9
// 960.092 us; speedup vs baseline: 1.4506x; 1.0462x over previous
//
#include <hip/hip_runtime.h>
#include <hip/hip_bf16.h>
#include <cstdint>

// ---------------------------------------------------------------------------
// LlamaMlpWithLora: T=2048, H=4096, I=11008, A=8, R=16, scale=0.5
// R9: 16-MFMA-grain phases + correctly-derived counted vmcnt.
//   pass1: 4 phases/K-tile. Stage A4+Bg2 @Ph0, Bu2 @Ph1 (for t+1).
//          Waits: vmcnt(8)@Ph1 (retires t's Bu2, 4-phase slack),
//                 vmcnt(2)@Ph3 (retires t+1's A4+Bg2, 2-3 phase slack).
//   pass2: 2 phases/K-tile, 3-buf 2-tile-deep, vmcnt(6)@Ph1.
//   LoRA folded into K; thin-GEMM LoRA projections.
// ---------------------------------------------------------------------------

#define T_TOK 2048
#define H_DIM 4096
#define I_DIM 11008
#define R_LORA 16
#define KA1 4352    // H + 128(gate) + 128(up)
#define KA2 11136   // I + 128(down)

typedef __bf16 bf16x8 __attribute__((ext_vector_type(8)));
typedef float f32x4 __attribute__((ext_vector_type(4)));

__device__ __forceinline__ float bf2f(unsigned short u) {
    union { unsigned int i; float f; } v;
    v.i = ((unsigned int)u) << 16;
    return v.f;
}
__device__ __forceinline__ unsigned short f2bf(float f) {
    __bf16 b = (__bf16)f;
    unsigned short u;
    __builtin_memcpy(&u, &b, 2);
    return u;
}
__device__ __forceinline__ void cvt8(const float* s, unsigned short* d) {
    float4 a = reinterpret_cast<const float4*>(s)[0];
    float4 b = reinterpret_cast<const float4*>(s)[1];
    uint4 o;
    o.x = (unsigned)f2bf(a.x) | ((unsigned)f2bf(a.y) << 16);
    o.y = (unsigned)f2bf(a.z) | ((unsigned)f2bf(a.w) << 16);
    o.z = (unsigned)f2bf(b.x) | ((unsigned)f2bf(b.y) << 16);
    o.w = (unsigned)f2bf(b.z) | ((unsigned)f2bf(b.w) << 16);
    *reinterpret_cast<uint4*>(d) = o;
}
__device__ __forceinline__ void gload_lds16(const void* g, void* l) {
    __builtin_amdgcn_global_load_lds(
        (const __attribute__((address_space(1))) void*)g,
        (__attribute__((address_space(3))) void*)l,
        16, 0, 0);
}

#define PH_PRE()                                              \
    __builtin_amdgcn_s_barrier();                             \
    asm volatile("s_waitcnt lgkmcnt(0)" ::: "memory");        \
    __builtin_amdgcn_sched_barrier(0);                        \
    __builtin_amdgcn_s_setprio(1)
#define PH_POST()                                             \
    __builtin_amdgcn_s_setprio(0);                            \
    __builtin_amdgcn_s_barrier()

// ---------------- small kernels --------------------------------------------
__global__ __launch_bounds__(256) void cvt_rows(
    const float* __restrict__ src, unsigned short* __restrict__ dst, int K)
{
    const int row = blockIdx.x;
    const int tid = threadIdx.x;
    const float* s = src + (size_t)row * K;
    unsigned short* d = dst + (size_t)row * K;
    for (int k = tid * 8; k < K; k += 256 * 8) cvt8(s + k, d + k);
}

__global__ __launch_bounds__(256) void build_xa_x(
    const float* __restrict__ x, unsigned short* __restrict__ xa)
{
    const int t = blockIdx.x;
    const int tid = threadIdx.x;
    const float* s = x + (size_t)t * H_DIM;
    unsigned short* d = xa + (size_t)t * KA1;
    for (int k = tid * 8; k < H_DIM; k += 2048) cvt8(s + k, d + k);
}

__global__ __launch_bounds__(256) void fill_xa_aug(
    const float* __restrict__ V, const int* __restrict__ idx,
    unsigned short* __restrict__ xa)
{
    const int t = blockIdx.x;
    const int tid = threadIdx.x;
    const int a = (tid & 127) >> 4;
    const float val = (a == idx[t]) ? 0.5f * V[(size_t)t * 256 + tid] : 0.f;
    xa[(size_t)t * KA1 + H_DIM + tid] = f2bf(val);
}

__global__ __launch_bounds__(128) void fill_ta(
    const float* __restrict__ V, const int* __restrict__ idx,
    unsigned short* __restrict__ t_aug)
{
    const int t = blockIdx.x;
    const int tid = threadIdx.x;
    const int a = tid >> 4;
    const float val = (a == idx[t]) ? 0.5f * V[(size_t)t * 128 + tid] : 0.f;
    t_aug[(size_t)t * KA2 + I_DIM + tid] = f2bf(val);
}

__global__ __launch_bounds__(256) void build_w_aug(
    const float* __restrict__ w, const float* __restrict__ wb,
    unsigned short* __restrict__ dst,
    int Nrows, int Ksrc, int Kdst, int self_off, int zero_off)
{
    const int c = blockIdx.x;
    const int tid = threadIdx.x;
    const float* src = w + (size_t)c * Ksrc;
    unsigned short* d = dst + (size_t)c * Kdst;
    for (int k = tid * 8; k < Ksrc; k += 256 * 8) cvt8(src + k, d + k);
    if (tid < 128) {
        const int a = tid >> 4, r = tid & 15;
        const float v = wb[(((size_t)a * Nrows) + c) * R_LORA + r];
        d[self_off + tid] = f2bf(v);
        if (zero_off >= 0) d[zero_off + tid] = 0;
    }
}

// ---------------- thin GEMM (R7-exact) -------------------------------------
__global__ __launch_bounds__(512) void gemm_thin(
    const unsigned short* __restrict__ A, int lda,
    const unsigned short* __restrict__ B, int ldb,
    float* __restrict__ out, int N, int K)
{
    __shared__ __align__(16) unsigned short As[128][64];
    __shared__ __align__(16) unsigned short Bs[128][64];

    const int tid = threadIdx.x;
    const int lane = tid & 63;
    const int wid = tid >> 6;
    const int wr = wid >> 2;
    const int wc = wid & 3;
    const int fr = lane & 15;
    const int hi = lane >> 4;
    const int fsw = fr & 7;

    const int bm0 = blockIdx.y * 128;
    const int bn0 = blockIdx.x * 128;

    const int srow = tid >> 3;
    const int sslot = tid & 7;
    const int gcol = (sslot ^ (srow & 7)) * 8;
    const unsigned short* Ag = A + (size_t)(bm0 + srow) * lda + gcol;
    const unsigned short* Bg = B + (size_t)(bn0 + srow) * ldb + gcol;
    const size_t halfA = (size_t)64 * lda;
    const size_t halfB = (size_t)64 * ldb;

    f32x4 acc[4][2] = {};

    for (int kt = 0; kt < K; kt += 64) {
        gload_lds16(Ag + kt,         &As[srow][sslot * 8]);
        gload_lds16(Ag + halfA + kt, &As[64 + srow][sslot * 8]);
        gload_lds16(Bg + kt,         &Bs[srow][sslot * 8]);
        gload_lds16(Bg + halfB + kt, &Bs[64 + srow][sslot * 8]);
        __syncthreads();
        #pragma unroll
        for (int kk = 0; kk < 2; ++kk) {
            bf16x8 a_[4], b_[2];
            #pragma unroll
            for (int m = 0; m < 4; ++m)
                a_[m] = *reinterpret_cast<const bf16x8*>(
                    &As[wr * 64 + m * 16 + fr][((kk * 4 + hi) ^ fsw) * 8]);
            #pragma unroll
            for (int n = 0; n < 2; ++n)
                b_[n] = *reinterpret_cast<const bf16x8*>(
                    &Bs[wc * 32 + n * 16 + fr][((kk * 4 + hi) ^ fsw) * 8]);
            #pragma unroll
            for (int m = 0; m < 4; ++m)
                #pragma unroll
                for (int n = 0; n < 2; ++n)
                    acc[m][n] = __builtin_amdgcn_mfma_f32_16x16x32_bf16(
                        a_[m], b_[n], acc[m][n], 0, 0, 0);
        }
        __syncthreads();
    }

    const int orow0 = bm0 + wr * 64 + hi * 4;
    const int ocol0 = bn0 + wc * 32 + fr;
    #pragma unroll
    for (int m = 0; m < 4; ++m)
        #pragma unroll
        for (int j = 0; j < 4; ++j) {
            const int row = orow0 + m * 16 + j;
            #pragma unroll
            for (int n = 0; n < 2; ++n)
                out[(size_t)row * N + ocol0 + n * 16] = acc[m][n][j];
        }
}

// ---------------- pass 1: fused gate+up, 4-phase counted pipeline ----------
// BM=256, BN=128, BK=64. 8 waves 4Mx2N, per-wave 64x64 per matrix.
// LDS rows: A 0-255, Bg 256-383, Bu 384-511; 2 buffers (128KB).
__global__ __launch_bounds__(512, 2) void gemm_fused_gu(
    const unsigned short* __restrict__ A,
    const unsigned short* __restrict__ Bg,
    const unsigned short* __restrict__ Bu,
    unsigned short* __restrict__ Tout)
{
    __shared__ __align__(16) unsigned short lds[2][512][64];

    const int tid = threadIdx.x;
    const int lane = tid & 63;
    const int wid = tid >> 6;
    const int wr = wid >> 1;           // 0..3
    const int wc = wid & 1;            // 0..1
    const int fr = lane & 15;
    const int hi = lane >> 4;
    const int fsw = fr & 7;

    const int bm0 = (blockIdx.x & 7) * 256;   // XCD-pinned A-slab (L2-hot)
    const int bn0 = (blockIdx.x >> 3) * 128;

    const int srow = tid >> 3;
    const int sslot = tid & 7;
    const int gcol = (sslot ^ (srow & 7)) * 8;
    const unsigned short* Ap  = A  + (size_t)(bm0 + srow) * KA1 + gcol;
    const unsigned short* Bgp = Bg + (size_t)(bn0 + srow) * KA1 + gcol;
    const unsigned short* Bup = Bu + (size_t)(bn0 + srow) * KA1 + gcol;

    f32x4 accg[4][4] = {};
    f32x4 accu[4][4] = {};

    const int nt = KA1 / 64;   // 68
    int cur = 0;

    auto stage_A = [&](int buf, int kt) {
        #pragma unroll
        for (int q = 0; q < 4; ++q)
            gload_lds16(Ap + (size_t)(q * 64) * KA1 + kt, &lds[buf][q * 64 + srow][sslot * 8]);
    };
    auto stage_G = [&](int buf, int kt) {
        gload_lds16(Bgp + kt,                    &lds[buf][256 + srow][sslot * 8]);
        gload_lds16(Bgp + (size_t)64 * KA1 + kt, &lds[buf][320 + srow][sslot * 8]);
    };
    auto stage_U = [&](int buf, int kt) {
        gload_lds16(Bup + kt,                    &lds[buf][384 + srow][sslot * 8]);
        gload_lds16(Bup + (size_t)64 * KA1 + kt, &lds[buf][448 + srow][sslot * 8]);
    };

    // prologue: tile 0 (A4,Bg2,Bu2); retire all but Bu2; sync
    stage_A(0, 0); stage_G(0, 0); stage_U(0, 0);
    asm volatile("s_waitcnt vmcnt(2)" ::: "memory");
    __builtin_amdgcn_s_barrier();

    bf16x8 a0[4], a1[4], b0[4], b1[4];

    for (int t = 0; t < nt; ++t) {
        const int nxt = cur ^ 1;
        const bool last = (t == nt - 1);
        const int ktn = (t + 1) * 64;

        // ---- Ph0: gate k0. stage A4+Bg2 (-> t+1) ----
        #pragma unroll
        for (int m = 0; m < 4; ++m)
            a0[m] = *reinterpret_cast<const bf16x8*>(
                &lds[cur][wr * 64 + m * 16 + fr][(hi ^ fsw) * 8]);
        #pragma unroll
        for (int n = 0; n < 4; ++n)
            b0[n] = *reinterpret_cast<const bf16x8*>(
                &lds[cur][256 + wc * 64 + n * 16 + fr][(hi ^ fsw) * 8]);
        if (!last) { stage_A(nxt, ktn); stage_G(nxt, ktn); }
        PH_PRE();
        #pragma unroll
        for (int m = 0; m < 4; ++m)
            #pragma unroll
            for (int n = 0; n < 4; ++n)
                accg[m][n] = __builtin_amdgcn_mfma_f32_16x16x32_bf16(
                    a0[m], b0[n], accg[m][n], 0, 0, 0);
        PH_POST();

        // ---- Ph1: gate k1. stage Bu2 (-> t+1); retire t's Bu2 ----
        #pragma unroll
        for (int m = 0; m < 4; ++m)
            a1[m] = *reinterpret_cast<const bf16x8*>(
                &lds[cur][wr * 64 + m * 16 + fr][(((4 + hi)) ^ fsw) * 8]);
        #pragma unroll
        for (int n = 0; n < 4; ++n)
            b1[n] = *reinterpret_cast<const bf16x8*>(
                &lds[cur][256 + wc * 64 + n * 16 + fr][(((4 + hi)) ^ fsw) * 8]);
        if (!last) stage_U(nxt, ktn);
        if (last) asm volatile("s_waitcnt vmcnt(0)" ::: "memory");
        else      asm volatile("s_waitcnt vmcnt(8)" ::: "memory");
        PH_PRE();
        #pragma unroll
        for (int m = 0; m < 4; ++m)
            #pragma unroll
            for (int n = 0; n < 4; ++n)
                accg[m][n] = __builtin_amdgcn_mfma_f32_16x16x32_bf16(
                    a1[m], b1[n], accg[m][n], 0, 0, 0);
        PH_POST();

        // ---- Ph2: up k0 ----
        #pragma unroll
        for (int n = 0; n < 4; ++n)
            b0[n] = *reinterpret_cast<const bf16x8*>(
                &lds[cur][384 + wc * 64 + n * 16 + fr][(hi ^ fsw) * 8]);
        PH_PRE();
        #pragma unroll
        for (int m = 0; m < 4; ++m)
            #pragma unroll
            for (int n = 0; n < 4; ++n)
                accu[m][n] = __builtin_amdgcn_mfma_f32_16x16x32_bf16(
                    a0[m], b0[n], accu[m][n], 0, 0, 0);
        PH_POST();

        // ---- Ph3: up k1. retire t+1's A4+Bg2 (keep Bu2 in flight) ----
        #pragma unroll
        for (int n = 0; n < 4; ++n)
            b1[n] = *reinterpret_cast<const bf16x8*>(
                &lds[cur][384 + wc * 64 + n * 16 + fr][(((4 + hi)) ^ fsw) * 8]);
        if (!last) asm volatile("s_waitcnt vmcnt(2)" ::: "memory");
        PH_PRE();
        #pragma unroll
        for (int m = 0; m < 4; ++m)
            #pragma unroll
            for (int n = 0; n < 4; ++n)
                accu[m][n] = __builtin_amdgcn_mfma_f32_16x16x32_bf16(
                    a1[m], b1[n], accu[m][n], 0, 0, 0);
        PH_POST();

        cur = nxt;
    }

    const int orow0 = bm0 + wr * 64 + hi * 4;
    const int ocol0 = bn0 + wc * 64 + fr;
    #pragma unroll
    for (int m = 0; m < 4; ++m)
        #pragma unroll
        for (int j = 0; j < 4; ++j) {
            const int row = orow0 + m * 16 + j;
            #pragma unroll
            for (int n = 0; n < 4; ++n) {
                const float g = accg[m][n][j];
                const float u = accu[m][n][j];
                const float sg = g / (1.f + __expf(-g));
                Tout[(size_t)row * KA2 + ocol0 + n * 16] = f2bf(sg * u);
            }
        }
}

// ---------------- pass 2: down, 2-phase 3-buffer 2-deep --------------------
// BM=256, BN=128. LDS rows: A 0-255, B 256-383; 3 buffers (144KB).
__global__ __launch_bounds__(512, 2) void gemm_down(
    const unsigned short* __restrict__ A,
    const unsigned short* __restrict__ B,
    float* __restrict__ out)
{
    __shared__ __align__(16) unsigned short lds[3][384][64];

    const int tid = threadIdx.x;
    const int lane = tid & 63;
    const int wid = tid >> 6;
    const int wr = wid >> 1;
    const int wc = wid & 1;
    const int fr = lane & 15;
    const int hi = lane >> 4;
    const int fsw = fr & 7;

    const int bm0 = (blockIdx.x & 7) * 256;
    const int bn0 = (blockIdx.x >> 3) * 128;

    const int srow = tid >> 3;
    const int sslot = tid & 7;
    const int gcol = (sslot ^ (srow & 7)) * 8;
    const unsigned short* Ap = A + (size_t)(bm0 + srow) * KA2 + gcol;
    const unsigned short* Bp = B + (size_t)(bn0 + srow) * KA2 + gcol;

    f32x4 acc[4][4] = {};

    const int nt = KA2 / 64;   // 174
    int cur = 0, st = 2;

    auto stage_A = [&](int buf, int kt) {
        #pragma unroll
        for (int q = 0; q < 4; ++q)
            gload_lds16(Ap + (size_t)(q * 64) * KA2 + kt, &lds[buf][q * 64 + srow][sslot * 8]);
    };
    auto stage_B = [&](int buf, int kt) {
        gload_lds16(Bp + kt,                    &lds[buf][256 + srow][sslot * 8]);
        gload_lds16(Bp + (size_t)64 * KA2 + kt, &lds[buf][320 + srow][sslot * 8]);
    };

    // prologue: tiles 0,1 staged; retire tile 0; sync
    stage_A(0, 0);  stage_B(0, 0);
    stage_A(1, 64); stage_B(1, 64);
    asm volatile("s_waitcnt vmcnt(6)" ::: "memory");
    __builtin_amdgcn_s_barrier();

    bf16x8 a0[4], a1[4], b0[4], b1[4];

    for (int t = 0; t < nt; ++t) {
        const bool has2 = (t + 2 < nt);
        const int ktn = (t + 2) * 64;

        // ---- Ph0: k0. stage A4 (-> t+2) ----
        #pragma unroll
        for (int m = 0; m < 4; ++m)
            a0[m] = *reinterpret_cast<const bf16x8*>(
                &lds[cur][wr * 64 + m * 16 + fr][(hi ^ fsw) * 8]);
        #pragma unroll
        for (int n = 0; n < 4; ++n)
            b0[n] = *reinterpret_cast<const bf16x8*>(
                &lds[cur][256 + wc * 64 + n * 16 + fr][(hi ^ fsw) * 8]);
        if (has2) stage_A(st, ktn);
        PH_PRE();
        #pragma unroll
        for (int m = 0; m < 4; ++m)
            #pragma unroll
            for (int n = 0; n < 4; ++n)
                acc[m][n] = __builtin_amdgcn_mfma_f32_16x16x32_bf16(
                    a0[m], b0[n], acc[m][n], 0, 0, 0);
        PH_POST();

        // ---- Ph1: k1. stage B2 (-> t+2); retire t+1's A4+B2 ----
        #pragma unroll
        for (int m = 0; m < 4; ++m)
            a1[m] = *reinterpret_cast<const bf16x8*>(
                &lds[cur][wr * 64 + m * 16 + fr][(((4 + hi)) ^ fsw) * 8]);
        #pragma unroll
        for (int n = 0; n < 4; ++n)
            b1[n] = *reinterpret_cast<const bf16x8*>(
                &lds[cur][256 + wc * 64 + n * 16 + fr][(((4 + hi)) ^ fsw) * 8]);
        if (has2) stage_B(st, ktn);
        if (t == nt - 2)     asm volatile("s_waitcnt vmcnt(0)" ::: "memory");
        else if (t < nt - 2) asm volatile("s_waitcnt vmcnt(6)" ::: "memory");
        PH_PRE();
        #pragma unroll
        for (int m = 0; m < 4; ++m)
            #pragma unroll
            for (int n = 0; n < 4; ++n)
                acc[m][n] = __builtin_amdgcn_mfma_f32_16x16x32_bf16(
                    a1[m], b1[n], acc[m][n], 0, 0, 0);
        PH_POST();

        cur = (cur == 2) ? 0 : cur + 1;
        st  = (st == 2) ? 0 : st + 1;
    }

    const int orow0 = bm0 + wr * 64 + hi * 4;
    const int ocol0 = bn0 + wc * 64 + fr;
    #pragma unroll
    for (int m = 0; m < 4; ++m)
        #pragma unroll
        for (int j = 0; j < 4; ++j) {
            const int row = orow0 + m * 16 + j;
            #pragma unroll
            for (int n = 0; n < 4; ++n)
                out[(size_t)row * H_DIM + ocol0 + n * 16] = acc[m][n][j];
        }
}

// ---------------------------------------------------------------------------
extern "C" void kernel_launch(void* const* d_in, const int* in_sizes, int n_in,
                              void* d_out, int out_size, void* d_ws, size_t ws_size,
                              hipStream_t stream)
{
    const float* x       = (const float*)d_in[0];
    const float* gate_w  = (const float*)d_in[1];
    const float* up_w    = (const float*)d_in[2];
    const float* down_w  = (const float*)d_in[3];
    const float* gate_wa = (const float*)d_in[4];
    const float* gate_wb = (const float*)d_in[5];
    const float* up_wa   = (const float*)d_in[6];
    const float* up_wb   = (const float*)d_in[7];
    const float* down_wa = (const float*)d_in[8];
    const float* down_wb = (const float*)d_in[9];
    const int*   indices = (const int*)d_in[10];
    float* out = (float*)d_out;

    char* ws = (char*)d_ws;
    size_t off = 0;
    auto alloc = [&](size_t bytes) {
        char* p = ws + off;
        off += (bytes + 255) & ~(size_t)255;
        return p;
    };
    unsigned short* xa     = (unsigned short*)alloc((size_t)T_TOK * KA1 * 2);
    unsigned short* wg_aug = (unsigned short*)alloc((size_t)I_DIM * KA1 * 2);
    unsigned short* wu_aug = (unsigned short*)alloc((size_t)I_DIM * KA1 * 2);
    unsigned short* t_aug  = (unsigned short*)alloc((size_t)T_TOK * KA2 * 2);
    unsigned short* wab_gu = (unsigned short*)alloc((size_t)256 * H_DIM * 2);
    float* Vgu = (float*)t_aug;                     // overlay, dead before pass1
    float* Vd  = (float*)wab_gu;                    // overlay, dead post-pass1
    unsigned short* wd_aug = wu_aug;                // reused after pass1
    unsigned short* wab_d  = wu_aug + (size_t)H_DIM * KA2;  // tail of wu slot

    // --- LoRA-A projections via thin GEMMs ---
    cvt_rows<<<128, 256, 0, stream>>>(gate_wa, wab_gu, H_DIM);
    cvt_rows<<<128, 256, 0, stream>>>(up_wa, wab_gu + (size_t)128 * H_DIM, H_DIM);
    build_xa_x<<<T_TOK, 256, 0, stream>>>(x, xa);
    gemm_thin<<<dim3(2, 16), 512, 0, stream>>>(xa, KA1, wab_gu, H_DIM, Vgu, 256, H_DIM);
    fill_xa_aug<<<T_TOK, 256, 0, stream>>>(Vgu, indices, xa);

    // --- augmented weights ---
    build_w_aug<<<I_DIM, 256, 0, stream>>>(gate_w, gate_wb, wg_aug,
                                           I_DIM, H_DIM, KA1, H_DIM, H_DIM + 128);
    build_w_aug<<<I_DIM, 256, 0, stream>>>(up_w, up_wb, wu_aug,
                                           I_DIM, H_DIM, KA1, H_DIM + 128, H_DIM);

    // --- pass 1: fused gate+up -> t. grid 8 bm x 86 bn ---
    gemm_fused_gu<<<8 * (I_DIM / 128), 512, 0, stream>>>(xa, wg_aug, wu_aug, t_aug);

    // --- down LoRA + weights ---
    cvt_rows<<<128, 256, 0, stream>>>(down_wa, wab_d, I_DIM);
    gemm_thin<<<dim3(1, 16), 512, 0, stream>>>(t_aug, KA2, wab_d, I_DIM, Vd, 128, I_DIM);
    fill_ta<<<T_TOK, 128, 0, stream>>>(Vd, indices, t_aug);
    build_w_aug<<<H_DIM, 256, 0, stream>>>(down_w, down_wb, wd_aug,
                                           H_DIM, I_DIM, KA2, I_DIM, -1);

    // --- pass 2: down -> out. grid 8 bm x 32 bn = 256 ---
    gemm_down<<<8 * (H_DIM / 128), 512, 0, stream>>>(t_aug, wd_aug, out);

    (void)in_sizes; (void)n_in; (void)out_size; (void)ws_size;
}